// Round 5
// baseline (470.857 us; speedup 1.0000x reference)
//
#include <hip/hip_runtime.h>
#include <hip/hip_bf16.h>

#define NEG_INF (-__builtin_inff())

typedef __attribute__((ext_vector_type(8))) short bf16x8;
typedef __attribute__((ext_vector_type(4))) float f32x4;

// ---------------- helpers ----------------
__device__ inline float wave_sum64(float v) {
#pragma unroll
  for (int m = 32; m >= 1; m >>= 1) v += __shfl_xor(v, m, 64);
  return v;
}
__device__ inline ushort f2bf(float f) {  // RNE float->bf16
  uint u = __float_as_uint(f);
  return (ushort)((u + 0x7FFFu + ((u >> 16) & 1u)) >> 16);
}

// ---------------- graph boundary kernel ----------------
__global__ void starts_kernel(const int* __restrict__ batch, int* __restrict__ starts,
                              int N, int G) {
  int i = blockIdx.x * blockDim.x + threadIdx.x;
  if (i >= N) return;
  int b = batch[i];
  if (i == 0) {
    for (int g = 0; g <= b; ++g) starts[g] = 0;
  } else {
    int bp = batch[i - 1];
    for (int g = bp + 1; g <= b; ++g) starts[g] = i;
  }
  if (i == N - 1) {
    for (int g = b + 1; g <= G; ++g) starts[g] = N;
  }
}

// ---------------- weight pack: f32 [K][N] -> bf16 [N][K] (B^T), all weights ----------------
__global__ __launch_bounds__(256) void pack_weights(
    const float* __restrict__ qkv_w, const float* __restrict__ out_w,
    const float* __restrict__ ff1_w, const float* __restrict__ ff2_w,
    const float* __restrict__ b1_w, const float* __restrict__ lat_w,
    short* __restrict__ qkv_t, short* __restrict__ out_t,
    short* __restrict__ ff1_t, short* __restrict__ ff2_t,
    short* __restrict__ b1_t, short* __restrict__ lat_t) {
  int t = blockIdx.x;
  const float* src;
  short* dst;
  int Kd, Nd, rem;
  if (t < 768) {
    int l = t / 192; rem = t % 192; Kd = 256; Nd = 768;
    src = qkv_w + (size_t)l * Kd * Nd; dst = qkv_t + (size_t)l * Nd * Kd;
  } else if (t < 1024) {
    t -= 768; int l = t / 64; rem = t % 64; Kd = 256; Nd = 256;
    src = out_w + (size_t)l * Kd * Nd; dst = out_t + (size_t)l * Nd * Kd;
  } else if (t < 2048) {
    t -= 1024; int l = t / 256; rem = t % 256; Kd = 256; Nd = 1024;
    src = ff1_w + (size_t)l * Kd * Nd; dst = ff1_t + (size_t)l * Nd * Kd;
  } else if (t < 3072) {
    t -= 2048; int l = t / 256; rem = t % 256; Kd = 1024; Nd = 256;
    src = ff2_w + (size_t)l * Kd * Nd; dst = ff2_t + (size_t)l * Nd * Kd;
  } else if (t < 3104) {
    rem = t - 3072; Kd = 256; Nd = 128; src = b1_w; dst = b1_t;
  } else {
    rem = t - 3104; Kd = 256; Nd = 32; src = lat_w; dst = lat_t;
  }
  const int ntn = Nd / 32;
  const int kt = rem / ntn, nt = rem % ntn;

  __shared__ float tile[32][33];
  const int tx = threadIdx.x & 31, ty = threadIdx.x >> 5;
#pragma unroll
  for (int r = 0; r < 4; ++r) {
    int k = kt * 32 + ty + r * 8;
    tile[ty + r * 8][tx] = src[(size_t)k * Nd + nt * 32 + tx];
  }
  __syncthreads();
#pragma unroll
  for (int r = 0; r < 4; ++r) {
    int n = nt * 32 + ty + r * 8;
    dst[(size_t)n * Kd + kt * 32 + tx] = (short)f2bf(tile[tx][ty + r * 8]);
  }
}

// ---------------- input projection: h = x @ Wi + bi  (K=16, D=256) ----------------
__global__ __launch_bounds__(256) void inproj_kernel(
    const float* __restrict__ x, const float* __restrict__ Wi,
    const float* __restrict__ bi, float* __restrict__ h) {
  __shared__ float xs[16];
  const int i = blockIdx.x, j = threadIdx.x;
  if (j < 16) xs[j] = x[(size_t)i * 16 + j];
  __syncthreads();
  float acc = bi[j];
#pragma unroll
  for (int k = 0; k < 16; ++k) acc += xs[k] * Wi[k * 256 + j];
  h[(size_t)i * 256 + j] = acc;
}

// ---------------- MFMA bf16 GEMM: C = act(A[M,K]_f32 @ B + bias), Bt = bf16 [N][K] ----------------
template <int ACT>
__global__ __launch_bounds__(256) void gemm_mfma(
    const float* __restrict__ A, const short* __restrict__ Bt,
    const float* __restrict__ bias, float* __restrict__ C,
    int M, int N, int K) {
  __shared__ short As[64 * 64];
  __shared__ short Bs[64 * 64];

  const int t = threadIdx.x;
  const int bm = blockIdx.y, bn = blockIdx.x;
  const int srow = t >> 2;
  const int spair = t & 3;

  const int lane = t & 63, wid = t >> 6;
  const int wr = wid >> 1, wc = wid & 1;
  const int fr = lane & 15, fs = lane >> 4;

  f32x4 acc[2][2];
#pragma unroll
  for (int m = 0; m < 2; ++m)
#pragma unroll
    for (int n = 0; n < 2; ++n) acc[m][n] = (f32x4){0.f, 0.f, 0.f, 0.f};

  const float* ap = A + (size_t)(bm * 64 + srow) * K + spair * 16;
  const int ng = bn * 64 + srow;
  const short* bp = Bt + (size_t)ng * K + spair * 16;

  const int ar0 = wr * 32 + fr, ar1 = ar0 + 16;
  const int bc0 = wc * 32 + fr, bc1 = bc0 + 16;

#define SLOT(base, row, slot) ((base) + (row) * 64 + (((slot) ^ ((row) & 7)) * 8))

  for (int k0 = 0; k0 < K; k0 += 64) {
    float4 f0 = *(const float4*)(ap + k0);
    float4 f1 = *(const float4*)(ap + k0 + 4);
    float4 f2 = *(const float4*)(ap + k0 + 8);
    float4 f3 = *(const float4*)(ap + k0 + 12);
    bf16x8 alo, ahi;
    alo[0] = f2bf(f0.x); alo[1] = f2bf(f0.y); alo[2] = f2bf(f0.z); alo[3] = f2bf(f0.w);
    alo[4] = f2bf(f1.x); alo[5] = f2bf(f1.y); alo[6] = f2bf(f1.z); alo[7] = f2bf(f1.w);
    ahi[0] = f2bf(f2.x); ahi[1] = f2bf(f2.y); ahi[2] = f2bf(f2.z); ahi[3] = f2bf(f2.w);
    ahi[4] = f2bf(f3.x); ahi[5] = f2bf(f3.y); ahi[6] = f2bf(f3.z); ahi[7] = f2bf(f3.w);
    *(bf16x8*)SLOT(As, srow, spair * 2) = alo;
    *(bf16x8*)SLOT(As, srow, spair * 2 + 1) = ahi;
    bf16x8 blo, bhi;
    if (ng < N) {
      blo = *(const bf16x8*)(bp + k0);
      bhi = *(const bf16x8*)(bp + k0 + 8);
    } else {
      blo = (bf16x8){0, 0, 0, 0, 0, 0, 0, 0};
      bhi = blo;
    }
    *(bf16x8*)SLOT(Bs, srow, spair * 2) = blo;
    *(bf16x8*)SLOT(Bs, srow, spair * 2 + 1) = bhi;
    __syncthreads();

#pragma unroll
    for (int ks = 0; ks < 2; ++ks) {
      const int slot = ks * 4 + fs;
      bf16x8 a0 = *(const bf16x8*)SLOT(As, ar0, slot);
      bf16x8 a1 = *(const bf16x8*)SLOT(As, ar1, slot);
      bf16x8 b0 = *(const bf16x8*)SLOT(Bs, bc0, slot);
      bf16x8 b1 = *(const bf16x8*)SLOT(Bs, bc1, slot);
      acc[0][0] = __builtin_amdgcn_mfma_f32_16x16x32_bf16(a0, b0, acc[0][0], 0, 0, 0);
      acc[0][1] = __builtin_amdgcn_mfma_f32_16x16x32_bf16(a0, b1, acc[0][1], 0, 0, 0);
      acc[1][0] = __builtin_amdgcn_mfma_f32_16x16x32_bf16(a1, b0, acc[1][0], 0, 0, 0);
      acc[1][1] = __builtin_amdgcn_mfma_f32_16x16x32_bf16(a1, b1, acc[1][1], 0, 0, 0);
    }
    __syncthreads();
  }
#undef SLOT

#pragma unroll
  for (int n = 0; n < 2; ++n) {
    const int col = bn * 64 + wc * 32 + n * 16 + fr;
    if (col >= N) continue;
    const float bv = bias[col];
#pragma unroll
    for (int m = 0; m < 2; ++m) {
      const int rbase = bm * 64 + wr * 32 + m * 16 + fs * 4;
#pragma unroll
      for (int j = 0; j < 4; ++j) {
        float v = acc[m][n][j] + bv;
        if (ACT == 1) v = fmaxf(v, 0.f);
        C[(size_t)(rbase + j) * N + col] = v;
      }
    }
  }
}

// ---------------- block-diagonal attention, 4 queries x 4 waves per block ----------------
// Block owns 4 consecutive queries. Each wave keeps all 4 Q-vectors in registers
// (lane l owns dims 4l..4l+3, head = l>>3) and flash-accumulates 4 independent
// online-softmax streams over a quarter of the union j-range; K/V row loads are
// coalesced and amortized over 4 queries (4x less L2 traffic, 4x ILP on the
// exp/shfl chain). Per-query validity mask handles graph-boundary straddling.
__global__ __launch_bounds__(256) void attn_kernel(
    const float* __restrict__ qkv, const int* __restrict__ starts,
    const int* __restrict__ batch, float* __restrict__ out) {
  __shared__ float red[4][4][64][6];  // [wave][q][lane][{m,l,ax,ay,az,aw}]
  const int qbase = blockIdx.x * 4;
  const int lane = threadIdx.x & 63;
  const int w = threadIdx.x >> 6;
  const float4 f4z = make_float4(0.f, 0.f, 0.f, 0.f);

  int jsq[4], jeq[4];
#pragma unroll
  for (int k = 0; k < 4; ++k) {
    const int b = batch[qbase + k];
    jsq[k] = starts[b];
    jeq[k] = starts[b + 1];
  }
  const int js = jsq[0], je = jeq[3];  // union (batch sorted)
  const int chunk = ((je - js) + 3) >> 2;
  const int s0 = js + w * chunk;
  const int s1 = min(s0 + chunk, je);

  const float scale = 0.17677669529663687f;  // 1/sqrt(32)
  float4 q[4];
#pragma unroll
  for (int k = 0; k < 4; ++k) {
    float4 qv = *(const float4*)(qkv + (size_t)(qbase + k) * 768 + lane * 4);
    q[k] = make_float4(qv.x * scale, qv.y * scale, qv.z * scale, qv.w * scale);
  }

  float m[4], l[4];
  float4 acc[4];
#pragma unroll
  for (int k = 0; k < 4; ++k) { m[k] = -3.0e38f; l[k] = 0.f; acc[k] = f4z; }

  const float* kb = qkv + 256 + lane * 4;
  const float* vb = qkv + 512 + lane * 4;

  float4 kc = (s0 < s1) ? *(const float4*)(kb + (size_t)s0 * 768) : f4z;
  float4 vc = (s0 < s1) ? *(const float4*)(vb + (size_t)s0 * 768) : f4z;

  for (int j = s0; j < s1; ++j) {
    const float4 kn = (j + 1 < s1) ? *(const float4*)(kb + (size_t)(j + 1) * 768) : f4z;
    const float4 vn = (j + 1 < s1) ? *(const float4*)(vb + (size_t)(j + 1) * 768) : f4z;
#pragma unroll
    for (int k = 0; k < 4; ++k) {
      float s = q[k].x * kc.x + q[k].y * kc.y + q[k].z * kc.z + q[k].w * kc.w;
      s += __shfl_xor(s, 1, 64);
      s += __shfl_xor(s, 2, 64);
      s += __shfl_xor(s, 4, 64);
      const bool valid = (j >= jsq[k]) && (j < jeq[k]);
      const float sv = valid ? s : -3.0e38f;
      const float mn = fmaxf(m[k], sv);
      const float corr = __expf(m[k] - mn);
      const float p = valid ? __expf(sv - mn) : 0.f;
      l[k] = l[k] * corr + p;
      acc[k].x = acc[k].x * corr + p * vc.x;
      acc[k].y = acc[k].y * corr + p * vc.y;
      acc[k].z = acc[k].z * corr + p * vc.z;
      acc[k].w = acc[k].w * corr + p * vc.w;
      m[k] = mn;
    }
    kc = kn; vc = vn;
  }

#pragma unroll
  for (int k = 0; k < 4; ++k) {
    red[w][k][lane][0] = m[k];
    red[w][k][lane][1] = l[k];
    red[w][k][lane][2] = acc[k].x; red[w][k][lane][3] = acc[k].y;
    red[w][k][lane][4] = acc[k].z; red[w][k][lane][5] = acc[k].w;
  }
  __syncthreads();

  // wave w merges query k=w
  {
    const int k = w;
    float M = red[0][k][lane][0];
#pragma unroll
    for (int ww = 1; ww < 4; ++ww) M = fmaxf(M, red[ww][k][lane][0]);
    float L = 0.f;
    float4 A = f4z;
#pragma unroll
    for (int ww = 0; ww < 4; ++ww) {
      const float c = __expf(red[ww][k][lane][0] - M);  // empty chunk: exp(-3e38-M)=0
      L += red[ww][k][lane][1] * c;
      A.x += red[ww][k][lane][2] * c; A.y += red[ww][k][lane][3] * c;
      A.z += red[ww][k][lane][4] * c; A.w += red[ww][k][lane][5] * c;
    }
    const float inv = 1.f / L;
    float4 o = make_float4(A.x * inv, A.y * inv, A.z * inv, A.w * inv);
    *(float4*)(out + (size_t)(qbase + k) * 256 + lane * 4) = o;
  }
}

// ---------------- fused residual + LayerNorm (D=256) ----------------
__global__ __launch_bounds__(256) void ln_kernel(
    const float* __restrict__ base, const float* __restrict__ delta,
    const float* __restrict__ s, const float* __restrict__ b,
    float* __restrict__ out) {
  const int row = blockIdx.x * 4 + (threadIdx.x >> 6);
  const int lane = threadIdx.x & 63;
  const float4 xa = *(const float4*)(base + (size_t)row * 256 + lane * 4);
  const float4 xb = *(const float4*)(delta + (size_t)row * 256 + lane * 4);
  float4 v = make_float4(xa.x + xb.x, xa.y + xb.y, xa.z + xb.z, xa.w + xb.w);
  float sum = v.x + v.y + v.z + v.w;
  sum = wave_sum64(sum);
  const float mean = sum * (1.f / 256.f);
  float4 d = make_float4(v.x - mean, v.y - mean, v.z - mean, v.w - mean);
  float sq = d.x * d.x + d.y * d.y + d.z * d.z + d.w * d.w;
  sq = wave_sum64(sq);
  const float rs = rsqrtf(sq * (1.f / 256.f) + 1e-5f);
  const float4 sv = *(const float4*)(s + lane * 4);
  const float4 bv = *(const float4*)(b + lane * 4);
  float4 o = make_float4(d.x * rs * sv.x + bv.x, d.y * rs * sv.y + bv.y,
                         d.z * rs * sv.z + bv.z, d.w * rs * sv.w + bv.w);
  *(float4*)(out + (size_t)row * 256 + lane * 4) = o;
}

// ---------------- lat normalization ----------------
__global__ __launch_bounds__(256) void latnorm_kernel(float* __restrict__ lat) {
  const int idx = blockIdx.x * 256 + threadIdx.x;
  const int row = idx >> 5;
  const int c = idx & 31;
  float v = lat[(size_t)row * 32 + c];
  float sq = v * v;
#pragma unroll
  for (int m = 16; m >= 1; m >>= 1) sq += __shfl_xor(sq, m, 32);
  const float norm = fmaxf(sqrtf(sq), 1e-12f);
  lat[(size_t)row * 32 + c] = v / norm * 5.656854249492381f;
}

// ---------------- beta head ----------------
__global__ __launch_bounds__(256) void beta_kernel(
    const float* __restrict__ bh, const float* __restrict__ w,
    const float* __restrict__ b2b, float* __restrict__ beta) {
  const int row = blockIdx.x * 4 + (threadIdx.x >> 6);
  const int lane = threadIdx.x & 63;
  float p = bh[(size_t)row * 128 + lane] * w[lane] +
            bh[(size_t)row * 128 + 64 + lane] * w[64 + lane];
  p = wave_sum64(p);
  if (lane == 0) {
    float x = p + b2b[0];
    float sgm = 1.f / (1.f + __expf(-x));
    sgm = fminf(fmaxf(sgm, 1e-6f), 1.f - 1e-6f);
    beta[row] = sgm;
  }
}

// ---------------- launch ----------------
extern "C" void kernel_launch(void* const* d_in, const int* in_sizes, int n_in,
                              void* d_out, int out_size, void* d_ws, size_t ws_size,
                              hipStream_t stream) {
  const int N = 2048, G = 16, D = 256, FF = 1024, L = 4;

  const float* x     = (const float*)d_in[0];
  const int*   batch = (const int*)d_in[2];
  const float* Wi    = (const float*)d_in[3];
  const float* bi    = (const float*)d_in[4];
  const float* qkv_w = (const float*)d_in[5];
  const float* qkv_b = (const float*)d_in[6];
  const float* out_w = (const float*)d_in[7];
  const float* out_b = (const float*)d_in[8];
  const float* ff1_w = (const float*)d_in[9];
  const float* ff1_b = (const float*)d_in[10];
  const float* ff2_w = (const float*)d_in[11];
  const float* ff2_b = (const float*)d_in[12];
  const float* ln1_s = (const float*)d_in[13];
  const float* ln1_b = (const float*)d_in[14];
  const float* ln2_s = (const float*)d_in[15];
  const float* ln2_b = (const float*)d_in[16];
  const float* lat_w = (const float*)d_in[17];
  const float* lat_b = (const float*)d_in[18];
  const float* b1_w  = (const float*)d_in[19];
  const float* b1_b  = (const float*)d_in[20];
  const float* b2_w  = (const float*)d_in[21];
  const float* b2_b  = (const float*)d_in[22];

  float* ws = (float*)d_ws;
  float* h       = ws;                       // N*D
  float* qkv     = h + (size_t)N * D;        // N*3D
  float* attnout = qkv + (size_t)N * 3 * D;  // N*D
  float* tmp     = attnout + (size_t)N * D;  // N*D
  float* ffbuf   = tmp + (size_t)N * D;      // N*FF
  float* bh      = ffbuf + (size_t)N * FF;   // N*128
  int*   starts  = (int*)(bh + (size_t)N * 128);  // G+1 (pad 32)
  short* wb      = (short*)(starts + 32);
  short* qkv_t = wb;                              // L*768*256
  short* out_t = qkv_t + (size_t)L * 768 * 256;   // L*256*256
  short* ff1_t = out_t + (size_t)L * 256 * 256;   // L*1024*256
  short* ff2_t = ff1_t + (size_t)L * 1024 * 256;  // L*256*1024
  short* b1_t  = ff2_t + (size_t)L * 256 * 1024;  // 128*256
  short* lat_t = b1_t + (size_t)128 * 256;        // 32*256

  float* beta_out = (float*)d_out;
  float* lat_out  = beta_out + N;

  pack_weights<<<3112, 256, 0, stream>>>(qkv_w, out_w, ff1_w, ff2_w, b1_w, lat_w,
                                         qkv_t, out_t, ff1_t, ff2_t, b1_t, lat_t);
  starts_kernel<<<(N + 255) / 256, 256, 0, stream>>>(batch, starts, N, G);
  inproj_kernel<<<N, 256, 0, stream>>>(x, Wi, bi, h);

  for (int l = 0; l < L; ++l) {
    gemm_mfma<0><<<dim3(768 / 64, N / 64), 256, 0, stream>>>(
        h, qkv_t + (size_t)l * 768 * 256, qkv_b + (size_t)l * 768, qkv, N, 768, 256);
    attn_kernel<<<N / 4, 256, 0, stream>>>(qkv, starts, batch, attnout);
    gemm_mfma<0><<<dim3(256 / 64, N / 64), 256, 0, stream>>>(
        attnout, out_t + (size_t)l * 256 * 256, out_b + (size_t)l * 256, tmp, N, 256, 256);
    ln_kernel<<<N / 4, 256, 0, stream>>>(h, tmp, ln1_s + (size_t)l * D, ln1_b + (size_t)l * D, h);
    gemm_mfma<1><<<dim3(FF / 64, N / 64), 256, 0, stream>>>(
        h, ff1_t + (size_t)l * FF * 256, ff1_b + (size_t)l * FF, ffbuf, N, FF, 256);
    gemm_mfma<0><<<dim3(256 / 64, N / 64), 256, 0, stream>>>(
        ffbuf, ff2_t + (size_t)l * 256 * FF, ff2_b + (size_t)l * 256, tmp, N, 256, FF);
    ln_kernel<<<N / 4, 256, 0, stream>>>(h, tmp, ln2_s + (size_t)l * D, ln2_b + (size_t)l * D, h);
  }

  gemm_mfma<0><<<dim3(1, N / 64), 256, 0, stream>>>(h, lat_t, lat_b, lat_out, N, 32, 256);
  latnorm_kernel<<<(N * 32) / 256, 256, 0, stream>>>(lat_out);

  gemm_mfma<1><<<dim3(2, N / 64), 256, 0, stream>>>(h, b1_t, b1_b, bh, N, 128, 256);
  beta_kernel<<<N / 4, 256, 0, stream>>>(bh, b2_w, b2_b, beta_out);
}

// Round 6
// 301.842 us; speedup vs baseline: 1.5599x; 1.5599x over previous
//
#include <hip/hip_runtime.h>
#include <hip/hip_bf16.h>

#define NEG_INF (-__builtin_inff())

typedef __attribute__((ext_vector_type(8))) short bf16x8;
typedef __attribute__((ext_vector_type(4))) float f32x4;

// ---------------- helpers ----------------
__device__ inline float wave_sum64(float v) {
#pragma unroll
  for (int m = 32; m >= 1; m >>= 1) v += __shfl_xor(v, m, 64);
  return v;
}
__device__ inline ushort f2bf(float f) {  // RNE float->bf16
  uint u = __float_as_uint(f);
  return (ushort)((u + 0x7FFFu + ((u >> 16) & 1u)) >> 16);
}

// ---------------- graph boundary kernel ----------------
__global__ void starts_kernel(const int* __restrict__ batch, int* __restrict__ starts,
                              int N, int G) {
  int i = blockIdx.x * blockDim.x + threadIdx.x;
  if (i >= N) return;
  int b = batch[i];
  if (i == 0) {
    for (int g = 0; g <= b; ++g) starts[g] = 0;
  } else {
    int bp = batch[i - 1];
    for (int g = bp + 1; g <= b; ++g) starts[g] = i;
  }
  if (i == N - 1) {
    for (int g = b + 1; g <= G; ++g) starts[g] = N;
  }
}

// ---------------- weight pack: f32 [K][N] -> bf16 [N][K] (B^T), all weights ----------------
__global__ __launch_bounds__(256) void pack_weights(
    const float* __restrict__ qkv_w, const float* __restrict__ out_w,
    const float* __restrict__ ff1_w, const float* __restrict__ ff2_w,
    const float* __restrict__ b1_w, const float* __restrict__ lat_w,
    short* __restrict__ qkv_t, short* __restrict__ out_t,
    short* __restrict__ ff1_t, short* __restrict__ ff2_t,
    short* __restrict__ b1_t, short* __restrict__ lat_t) {
  int t = blockIdx.x;
  const float* src;
  short* dst;
  int Kd, Nd, rem;
  if (t < 768) {
    int l = t / 192; rem = t % 192; Kd = 256; Nd = 768;
    src = qkv_w + (size_t)l * Kd * Nd; dst = qkv_t + (size_t)l * Nd * Kd;
  } else if (t < 1024) {
    t -= 768; int l = t / 64; rem = t % 64; Kd = 256; Nd = 256;
    src = out_w + (size_t)l * Kd * Nd; dst = out_t + (size_t)l * Nd * Kd;
  } else if (t < 2048) {
    t -= 1024; int l = t / 256; rem = t % 256; Kd = 256; Nd = 1024;
    src = ff1_w + (size_t)l * Kd * Nd; dst = ff1_t + (size_t)l * Nd * Kd;
  } else if (t < 3072) {
    t -= 2048; int l = t / 256; rem = t % 256; Kd = 1024; Nd = 256;
    src = ff2_w + (size_t)l * Kd * Nd; dst = ff2_t + (size_t)l * Nd * Kd;
  } else if (t < 3104) {
    rem = t - 3072; Kd = 256; Nd = 128; src = b1_w; dst = b1_t;
  } else {
    rem = t - 3104; Kd = 256; Nd = 32; src = lat_w; dst = lat_t;
  }
  const int ntn = Nd / 32;
  const int kt = rem / ntn, nt = rem % ntn;

  __shared__ float tile[32][33];
  const int tx = threadIdx.x & 31, ty = threadIdx.x >> 5;
#pragma unroll
  for (int r = 0; r < 4; ++r) {
    int k = kt * 32 + ty + r * 8;
    tile[ty + r * 8][tx] = src[(size_t)k * Nd + nt * 32 + tx];
  }
  __syncthreads();
#pragma unroll
  for (int r = 0; r < 4; ++r) {
    int n = nt * 32 + ty + r * 8;
    dst[(size_t)n * Kd + kt * 32 + tx] = (short)f2bf(tile[tx][ty + r * 8]);
  }
}

// ---------------- input projection: h = x @ Wi + bi  (K=16, D=256) ----------------
__global__ __launch_bounds__(256) void inproj_kernel(
    const float* __restrict__ x, const float* __restrict__ Wi,
    const float* __restrict__ bi, float* __restrict__ h) {
  __shared__ float xs[16];
  const int i = blockIdx.x, j = threadIdx.x;
  if (j < 16) xs[j] = x[(size_t)i * 16 + j];
  __syncthreads();
  float acc = bi[j];
#pragma unroll
  for (int k = 0; k < 16; ++k) acc += xs[k] * Wi[k * 256 + j];
  h[(size_t)i * 256 + j] = acc;
}

// ---------------- MFMA bf16 GEMM: C = act(A[M,K]_f32 @ B + bias), Bt = bf16 [N][K] ----------------
template <int ACT>
__global__ __launch_bounds__(256) void gemm_mfma(
    const float* __restrict__ A, const short* __restrict__ Bt,
    const float* __restrict__ bias, float* __restrict__ C,
    int M, int N, int K) {
  __shared__ short As[64 * 64];
  __shared__ short Bs[64 * 64];

  const int t = threadIdx.x;
  const int bm = blockIdx.y, bn = blockIdx.x;
  const int srow = t >> 2;
  const int spair = t & 3;

  const int lane = t & 63, wid = t >> 6;
  const int wr = wid >> 1, wc = wid & 1;
  const int fr = lane & 15, fs = lane >> 4;

  f32x4 acc[2][2];
#pragma unroll
  for (int m = 0; m < 2; ++m)
#pragma unroll
    for (int n = 0; n < 2; ++n) acc[m][n] = (f32x4){0.f, 0.f, 0.f, 0.f};

  const float* ap = A + (size_t)(bm * 64 + srow) * K + spair * 16;
  const int ng = bn * 64 + srow;
  const short* bp = Bt + (size_t)ng * K + spair * 16;

  const int ar0 = wr * 32 + fr, ar1 = ar0 + 16;
  const int bc0 = wc * 32 + fr, bc1 = bc0 + 16;

#define SLOT(base, row, slot) ((base) + (row) * 64 + (((slot) ^ ((row) & 7)) * 8))

  for (int k0 = 0; k0 < K; k0 += 64) {
    float4 f0 = *(const float4*)(ap + k0);
    float4 f1 = *(const float4*)(ap + k0 + 4);
    float4 f2 = *(const float4*)(ap + k0 + 8);
    float4 f3 = *(const float4*)(ap + k0 + 12);
    bf16x8 alo, ahi;
    alo[0] = f2bf(f0.x); alo[1] = f2bf(f0.y); alo[2] = f2bf(f0.z); alo[3] = f2bf(f0.w);
    alo[4] = f2bf(f1.x); alo[5] = f2bf(f1.y); alo[6] = f2bf(f1.z); alo[7] = f2bf(f1.w);
    ahi[0] = f2bf(f2.x); ahi[1] = f2bf(f2.y); ahi[2] = f2bf(f2.z); ahi[3] = f2bf(f2.w);
    ahi[4] = f2bf(f3.x); ahi[5] = f2bf(f3.y); ahi[6] = f2bf(f3.z); ahi[7] = f2bf(f3.w);
    *(bf16x8*)SLOT(As, srow, spair * 2) = alo;
    *(bf16x8*)SLOT(As, srow, spair * 2 + 1) = ahi;
    bf16x8 blo, bhi;
    if (ng < N) {
      blo = *(const bf16x8*)(bp + k0);
      bhi = *(const bf16x8*)(bp + k0 + 8);
    } else {
      blo = (bf16x8){0, 0, 0, 0, 0, 0, 0, 0};
      bhi = blo;
    }
    *(bf16x8*)SLOT(Bs, srow, spair * 2) = blo;
    *(bf16x8*)SLOT(Bs, srow, spair * 2 + 1) = bhi;
    __syncthreads();

#pragma unroll
    for (int ks = 0; ks < 2; ++ks) {
      const int slot = ks * 4 + fs;
      bf16x8 a0 = *(const bf16x8*)SLOT(As, ar0, slot);
      bf16x8 a1 = *(const bf16x8*)SLOT(As, ar1, slot);
      bf16x8 b0 = *(const bf16x8*)SLOT(Bs, bc0, slot);
      bf16x8 b1 = *(const bf16x8*)SLOT(Bs, bc1, slot);
      acc[0][0] = __builtin_amdgcn_mfma_f32_16x16x32_bf16(a0, b0, acc[0][0], 0, 0, 0);
      acc[0][1] = __builtin_amdgcn_mfma_f32_16x16x32_bf16(a0, b1, acc[0][1], 0, 0, 0);
      acc[1][0] = __builtin_amdgcn_mfma_f32_16x16x32_bf16(a1, b0, acc[1][0], 0, 0, 0);
      acc[1][1] = __builtin_amdgcn_mfma_f32_16x16x32_bf16(a1, b1, acc[1][1], 0, 0, 0);
    }
    __syncthreads();
  }
#undef SLOT

#pragma unroll
  for (int n = 0; n < 2; ++n) {
    const int col = bn * 64 + wc * 32 + n * 16 + fr;
    if (col >= N) continue;
    const float bv = bias[col];
#pragma unroll
    for (int m = 0; m < 2; ++m) {
      const int rbase = bm * 64 + wr * 32 + m * 16 + fs * 4;
#pragma unroll
      for (int j = 0; j < 4; ++j) {
        float v = acc[m][n][j] + bv;
        if (ACT == 1) v = fmaxf(v, 0.f);
        C[(size_t)(rbase + j) * N + col] = v;
      }
    }
  }
}

// ---------------- MFMA block-diagonal flash attention ----------------
// One block per (graph g, head h); 4 waves; wave owns q-tiles {w, w+4, w+8, w+12}
// (16 rows each, supports graphs up to 256 nodes). Flash over 128-wide j-chunks:
// stage K bf16 [128][40] (pad -> conflict-free) + V^T bf16 [32][128] (slot-XOR
// swizzled); S-tile = mfma(Q,K) with K=32=head_dim; online softmax in C/D layout
// (lane owns col j=fr, rows q=fs*4+reg); P -> bf16 -> swizzled LDS; PV = mfma(P,Vt).
__global__ __launch_bounds__(256) void attn_mfma(
    const float* __restrict__ qkv, const int* __restrict__ starts,
    float* __restrict__ out) {
  const int g = blockIdx.x >> 3;
  const int h = blockIdx.x & 7;
  const int t = threadIdx.x;
  const int lane = t & 63, w = t >> 6;
  const int fr = lane & 15, fs = lane >> 4;
  const int js = starts[g], je = starts[g + 1];
  const int Lg = je - js;

  __shared__ __align__(16) short Ks[128][40];
  __shared__ __align__(16) short Vt[32][128];
  __shared__ __align__(16) short Ps[4][16][128];

  const float scale = 0.17677669529663687f;  // 1/sqrt(32), folded into Q

  bf16x8 qf[4];
  f32x4 oa[4][2];
  float mrow[4][4], lrow[4][4];
#pragma unroll
  for (int tt = 0; tt < 4; ++tt) {
    const int q0 = js + (w + tt * 4) * 16;
    const int row = min(q0 + fr, 2047);
    const float* qp = qkv + (size_t)row * 768 + h * 32 + fs * 8;
    const float4 a = *(const float4*)qp;
    const float4 b = *(const float4*)(qp + 4);
    qf[tt][0] = (short)f2bf(a.x * scale); qf[tt][1] = (short)f2bf(a.y * scale);
    qf[tt][2] = (short)f2bf(a.z * scale); qf[tt][3] = (short)f2bf(a.w * scale);
    qf[tt][4] = (short)f2bf(b.x * scale); qf[tt][5] = (short)f2bf(b.y * scale);
    qf[tt][6] = (short)f2bf(b.z * scale); qf[tt][7] = (short)f2bf(b.w * scale);
    oa[tt][0] = (f32x4){0.f, 0.f, 0.f, 0.f};
    oa[tt][1] = (f32x4){0.f, 0.f, 0.f, 0.f};
#pragma unroll
    for (int j = 0; j < 4; ++j) { mrow[tt][j] = -3.0e38f; lrow[tt][j] = 0.f; }
  }

  const int nch = (Lg + 127) >> 7;
  for (int c = 0; c < nch; ++c) {
    const int c0 = js + (c << 7);
    __syncthreads();  // protect K/V from overwrite while prior chunk computes
    {
      const int r = t >> 1, half = t & 1;
      const int jr = c0 + r;
      float4 k0, k1, k2, k3, v0, v1, v2, v3;
      if (jr < je) {
        const float* kp = qkv + (size_t)jr * 768 + 256 + h * 32 + half * 16;
        k0 = *(const float4*)kp;       k1 = *(const float4*)(kp + 4);
        k2 = *(const float4*)(kp + 8); k3 = *(const float4*)(kp + 12);
        const float* vp = kp + 256;
        v0 = *(const float4*)vp;       v1 = *(const float4*)(vp + 4);
        v2 = *(const float4*)(vp + 8); v3 = *(const float4*)(vp + 12);
      } else {
        k0 = k1 = k2 = k3 = v0 = v1 = v2 = v3 = make_float4(0.f, 0.f, 0.f, 0.f);
      }
      short* kd = &Ks[r][half * 16];
      kd[0] = (short)f2bf(k0.x); kd[1] = (short)f2bf(k0.y);
      kd[2] = (short)f2bf(k0.z); kd[3] = (short)f2bf(k0.w);
      kd[4] = (short)f2bf(k1.x); kd[5] = (short)f2bf(k1.y);
      kd[6] = (short)f2bf(k1.z); kd[7] = (short)f2bf(k1.w);
      kd[8] = (short)f2bf(k2.x); kd[9] = (short)f2bf(k2.y);
      kd[10] = (short)f2bf(k2.z); kd[11] = (short)f2bf(k2.w);
      kd[12] = (short)f2bf(k3.x); kd[13] = (short)f2bf(k3.y);
      kd[14] = (short)f2bf(k3.z); kd[15] = (short)f2bf(k3.w);
      float vv[16] = {v0.x, v0.y, v0.z, v0.w, v1.x, v1.y, v1.z, v1.w,
                      v2.x, v2.y, v2.z, v2.w, v3.x, v3.y, v3.z, v3.w};
#pragma unroll
      for (int i = 0; i < 16; ++i) {
        const int d = half * 16 + i;
        Vt[d][((((r >> 3) ^ (d & 7)) << 3) | (r & 7))] = (short)f2bf(vv[i]);
      }
    }
    __syncthreads();

#pragma unroll
    for (int tt = 0; tt < 4; ++tt) {
      if ((w + tt * 4) * 16 >= Lg) continue;
      f32x4 s[8];
#pragma unroll
      for (int jt = 0; jt < 8; ++jt) {
        const bf16x8 kf = *(const bf16x8*)&Ks[jt * 16 + fr][fs * 8];
        s[jt] = __builtin_amdgcn_mfma_f32_16x16x32_bf16(
            qf[tt], kf, (f32x4){0.f, 0.f, 0.f, 0.f}, 0, 0, 0);
      }
      // mask invalid cols (beyond graph end)
#pragma unroll
      for (int jt = 0; jt < 8; ++jt) {
        const bool valid = (c0 + jt * 16 + fr) < je;
#pragma unroll
        for (int j = 0; j < 4; ++j) s[jt][j] = valid ? s[jt][j] : -3.0e38f;
      }
      // online softmax per q-row (lane owns col fr; rows = fs*4+j)
#pragma unroll
      for (int j = 0; j < 4; ++j) {
        float mx = s[0][j];
#pragma unroll
        for (int jt = 1; jt < 8; ++jt) mx = fmaxf(mx, s[jt][j]);
        mx = fmaxf(mx, __shfl_xor(mx, 1, 64));
        mx = fmaxf(mx, __shfl_xor(mx, 2, 64));
        mx = fmaxf(mx, __shfl_xor(mx, 4, 64));
        mx = fmaxf(mx, __shfl_xor(mx, 8, 64));
        const float mn = fmaxf(mrow[tt][j], mx);
        const float corr = __expf(mrow[tt][j] - mn);
        mrow[tt][j] = mn;
        float rs = 0.f;
#pragma unroll
        for (int jt = 0; jt < 8; ++jt) {
          const float p = __expf(s[jt][j] - mn);
          s[jt][j] = p;
          rs += p;
        }
        rs += __shfl_xor(rs, 1, 64);
        rs += __shfl_xor(rs, 2, 64);
        rs += __shfl_xor(rs, 4, 64);
        rs += __shfl_xor(rs, 8, 64);
        lrow[tt][j] = lrow[tt][j] * corr + rs;
        oa[tt][0][j] *= corr;
        oa[tt][1][j] *= corr;
      }
      // P -> bf16 -> swizzled LDS strip (per-wave private)
#pragma unroll
      for (int jt = 0; jt < 8; ++jt) {
#pragma unroll
        for (int j = 0; j < 4; ++j) {
          const int q = fs * 4 + j;
          Ps[w][q][((((jt * 2 + (fr >> 3)) ^ (q & 7)) << 3) | (fr & 7))] =
              (short)f2bf(s[jt][j]);
        }
      }
      // PV: A = P rows (q=fr), B = Vt rows (d = nt*16+fr), k = j
#pragma unroll
      for (int jq = 0; jq < 4; ++jq) {
        const int slot = ((jq * 4 + fs) ^ (fr & 7)) << 3;
        const bf16x8 pf = *(const bf16x8*)&Ps[w][fr][slot];
#pragma unroll
        for (int nt = 0; nt < 2; ++nt) {
          const bf16x8 vf = *(const bf16x8*)&Vt[nt * 16 + fr][slot];
          oa[tt][nt] = __builtin_amdgcn_mfma_f32_16x16x32_bf16(pf, vf, oa[tt][nt], 0, 0, 0);
        }
      }
    }
  }

  // epilogue: O = acc / l
#pragma unroll
  for (int tt = 0; tt < 4; ++tt) {
    if ((w + tt * 4) * 16 >= Lg) continue;
    const int q0 = js + (w + tt * 4) * 16;
#pragma unroll
    for (int j = 0; j < 4; ++j) {
      const int node = q0 + fs * 4 + j;
      if (node < je) {
        const float inv = 1.f / lrow[tt][j];
        out[(size_t)node * 256 + h * 32 + fr] = oa[tt][0][j] * inv;
        out[(size_t)node * 256 + h * 32 + 16 + fr] = oa[tt][1][j] * inv;
      }
    }
  }
}

// ---------------- fused residual + LayerNorm (D=256) ----------------
__global__ __launch_bounds__(256) void ln_kernel(
    const float* __restrict__ base, const float* __restrict__ delta,
    const float* __restrict__ s, const float* __restrict__ b,
    float* __restrict__ out) {
  const int row = blockIdx.x * 4 + (threadIdx.x >> 6);
  const int lane = threadIdx.x & 63;
  const float4 xa = *(const float4*)(base + (size_t)row * 256 + lane * 4);
  const float4 xb = *(const float4*)(delta + (size_t)row * 256 + lane * 4);
  float4 v = make_float4(xa.x + xb.x, xa.y + xb.y, xa.z + xb.z, xa.w + xb.w);
  float sum = v.x + v.y + v.z + v.w;
  sum = wave_sum64(sum);
  const float mean = sum * (1.f / 256.f);
  float4 d = make_float4(v.x - mean, v.y - mean, v.z - mean, v.w - mean);
  float sq = d.x * d.x + d.y * d.y + d.z * d.z + d.w * d.w;
  sq = wave_sum64(sq);
  const float rs = rsqrtf(sq * (1.f / 256.f) + 1e-5f);
  const float4 sv = *(const float4*)(s + lane * 4);
  const float4 bv = *(const float4*)(b + lane * 4);
  float4 o = make_float4(d.x * rs * sv.x + bv.x, d.y * rs * sv.y + bv.y,
                         d.z * rs * sv.z + bv.z, d.w * rs * sv.w + bv.w);
  *(float4*)(out + (size_t)row * 256 + lane * 4) = o;
}

// ---------------- lat normalization ----------------
__global__ __launch_bounds__(256) void latnorm_kernel(float* __restrict__ lat) {
  const int idx = blockIdx.x * 256 + threadIdx.x;
  const int row = idx >> 5;
  const int c = idx & 31;
  float v = lat[(size_t)row * 32 + c];
  float sq = v * v;
#pragma unroll
  for (int m = 16; m >= 1; m >>= 1) sq += __shfl_xor(sq, m, 32);
  const float norm = fmaxf(sqrtf(sq), 1e-12f);
  lat[(size_t)row * 32 + c] = v / norm * 5.656854249492381f;
}

// ---------------- beta head ----------------
__global__ __launch_bounds__(256) void beta_kernel(
    const float* __restrict__ bh, const float* __restrict__ w,
    const float* __restrict__ b2b, float* __restrict__ beta) {
  const int row = blockIdx.x * 4 + (threadIdx.x >> 6);
  const int lane = threadIdx.x & 63;
  float p = bh[(size_t)row * 128 + lane] * w[lane] +
            bh[(size_t)row * 128 + 64 + lane] * w[64 + lane];
  p = wave_sum64(p);
  if (lane == 0) {
    float x = p + b2b[0];
    float sgm = 1.f / (1.f + __expf(-x));
    sgm = fminf(fmaxf(sgm, 1e-6f), 1.f - 1e-6f);
    beta[row] = sgm;
  }
}

// ---------------- launch ----------------
extern "C" void kernel_launch(void* const* d_in, const int* in_sizes, int n_in,
                              void* d_out, int out_size, void* d_ws, size_t ws_size,
                              hipStream_t stream) {
  const int N = 2048, G = 16, D = 256, FF = 1024, L = 4;

  const float* x     = (const float*)d_in[0];
  const int*   batch = (const int*)d_in[2];
  const float* Wi    = (const float*)d_in[3];
  const float* bi    = (const float*)d_in[4];
  const float* qkv_w = (const float*)d_in[5];
  const float* qkv_b = (const float*)d_in[6];
  const float* out_w = (const float*)d_in[7];
  const float* out_b = (const float*)d_in[8];
  const float* ff1_w = (const float*)d_in[9];
  const float* ff1_b = (const float*)d_in[10];
  const float* ff2_w = (const float*)d_in[11];
  const float* ff2_b = (const float*)d_in[12];
  const float* ln1_s = (const float*)d_in[13];
  const float* ln1_b = (const float*)d_in[14];
  const float* ln2_s = (const float*)d_in[15];
  const float* ln2_b = (const float*)d_in[16];
  const float* lat_w = (const float*)d_in[17];
  const float* lat_b = (const float*)d_in[18];
  const float* b1_w  = (const float*)d_in[19];
  const float* b1_b  = (const float*)d_in[20];
  const float* b2_w  = (const float*)d_in[21];
  const float* b2_b  = (const float*)d_in[22];

  float* ws = (float*)d_ws;
  float* h       = ws;                       // N*D
  float* qkv     = h + (size_t)N * D;        // N*3D
  float* attnout = qkv + (size_t)N * 3 * D;  // N*D
  float* tmp     = attnout + (size_t)N * D;  // N*D
  float* ffbuf   = tmp + (size_t)N * D;      // N*FF
  float* bh      = ffbuf + (size_t)N * FF;   // N*128
  int*   starts  = (int*)(bh + (size_t)N * 128);  // G+1 (pad 32)
  short* wb      = (short*)(starts + 32);
  short* qkv_t = wb;                              // L*768*256
  short* out_t = qkv_t + (size_t)L * 768 * 256;   // L*256*256
  short* ff1_t = out_t + (size_t)L * 256 * 256;   // L*1024*256
  short* ff2_t = ff1_t + (size_t)L * 1024 * 256;  // L*256*1024
  short* b1_t  = ff2_t + (size_t)L * 256 * 1024;  // 128*256
  short* lat_t = b1_t + (size_t)128 * 256;        // 32*256

  float* beta_out = (float*)d_out;
  float* lat_out  = beta_out + N;

  pack_weights<<<3112, 256, 0, stream>>>(qkv_w, out_w, ff1_w, ff2_w, b1_w, lat_w,
                                         qkv_t, out_t, ff1_t, ff2_t, b1_t, lat_t);
  starts_kernel<<<(N + 255) / 256, 256, 0, stream>>>(batch, starts, N, G);
  inproj_kernel<<<N, 256, 0, stream>>>(x, Wi, bi, h);

  for (int l = 0; l < L; ++l) {
    gemm_mfma<0><<<dim3(768 / 64, N / 64), 256, 0, stream>>>(
        h, qkv_t + (size_t)l * 768 * 256, qkv_b + (size_t)l * 768, qkv, N, 768, 256);
    attn_mfma<<<G * 8, 256, 0, stream>>>(qkv, starts, attnout);
    gemm_mfma<0><<<dim3(256 / 64, N / 64), 256, 0, stream>>>(
        attnout, out_t + (size_t)l * 256 * 256, out_b + (size_t)l * 256, tmp, N, 256, 256);
    ln_kernel<<<N / 4, 256, 0, stream>>>(h, tmp, ln1_s + (size_t)l * D, ln1_b + (size_t)l * D, h);
    gemm_mfma<1><<<dim3(FF / 64, N / 64), 256, 0, stream>>>(
        h, ff1_t + (size_t)l * FF * 256, ff1_b + (size_t)l * FF, ffbuf, N, FF, 256);
    gemm_mfma<0><<<dim3(256 / 64, N / 64), 256, 0, stream>>>(
        ffbuf, ff2_t + (size_t)l * 256 * FF, ff2_b + (size_t)l * 256, tmp, N, 256, FF);
    ln_kernel<<<N / 4, 256, 0, stream>>>(h, tmp, ln2_s + (size_t)l * D, ln2_b + (size_t)l * D, h);
  }

  gemm_mfma<0><<<dim3(1, N / 64), 256, 0, stream>>>(h, lat_t, lat_b, lat_out, N, 32, 256);
  latnorm_kernel<<<(N * 32) / 256, 256, 0, stream>>>(lat_out);

  gemm_mfma<1><<<dim3(2, N / 64), 256, 0, stream>>>(h, b1_t, b1_b, bh, N, 128, 256);
  beta_kernel<<<N / 4, 256, 0, stream>>>(bh, b2_w, b2_b, beta_out);
}

// Round 7
// 213.389 us; speedup vs baseline: 2.2066x; 1.4145x over previous
//
#include <hip/hip_runtime.h>
#include <hip/hip_bf16.h>

typedef __attribute__((ext_vector_type(8))) short bf16x8;
typedef __attribute__((ext_vector_type(4))) float f32x4;

// ---------------- helpers ----------------
__device__ inline float wave_sum64(float v) {
#pragma unroll
  for (int m = 32; m >= 1; m >>= 1) v += __shfl_xor(v, m, 64);
  return v;
}
__device__ inline ushort f2bf(float f) {  // RNE float->bf16
  uint u = __float_as_uint(f);
  return (ushort)((u + 0x7FFFu + ((u >> 16) & 1u)) >> 16);
}

// ---------------- weight pack (f32 [K][N] -> bf16 [N][K]) + fused starts ----------------
__global__ __launch_bounds__(256) void pack_weights(
    const float* __restrict__ qkv_w, const float* __restrict__ out_w,
    const float* __restrict__ ff1_w, const float* __restrict__ ff2_w,
    const float* __restrict__ b1_w, const float* __restrict__ lat_w,
    short* __restrict__ qkv_t, short* __restrict__ out_t,
    short* __restrict__ ff1_t, short* __restrict__ ff2_t,
    short* __restrict__ b1_t, short* __restrict__ lat_t,
    const int* __restrict__ batch, int* __restrict__ starts) {
  int t = blockIdx.x;
  if (t == 3112) {  // fused graph-boundary computation
    for (int i = threadIdx.x; i < 2048; i += 256) {
      int b = batch[i];
      if (i == 0) {
        for (int g = 0; g <= b; ++g) starts[g] = 0;
      } else {
        int bp = batch[i - 1];
        for (int g = bp + 1; g <= b; ++g) starts[g] = i;
      }
      if (i == 2047) {
        for (int g = b + 1; g <= 16; ++g) starts[g] = 2048;
      }
    }
    return;
  }
  const float* src;
  short* dst;
  int Kd, Nd, rem;
  if (t < 768) {
    int l = t / 192; rem = t % 192; Kd = 256; Nd = 768;
    src = qkv_w + (size_t)l * Kd * Nd; dst = qkv_t + (size_t)l * Nd * Kd;
  } else if (t < 1024) {
    t -= 768; int l = t / 64; rem = t % 64; Kd = 256; Nd = 256;
    src = out_w + (size_t)l * Kd * Nd; dst = out_t + (size_t)l * Nd * Kd;
  } else if (t < 2048) {
    t -= 1024; int l = t / 256; rem = t % 256; Kd = 256; Nd = 1024;
    src = ff1_w + (size_t)l * Kd * Nd; dst = ff1_t + (size_t)l * Nd * Kd;
  } else if (t < 3072) {
    t -= 2048; int l = t / 256; rem = t % 256; Kd = 1024; Nd = 256;
    src = ff2_w + (size_t)l * Kd * Nd; dst = ff2_t + (size_t)l * Nd * Kd;
  } else if (t < 3104) {
    rem = t - 3072; Kd = 256; Nd = 128; src = b1_w; dst = b1_t;
  } else {
    rem = t - 3104; Kd = 256; Nd = 32; src = lat_w; dst = lat_t;
  }
  const int ntn = Nd / 32;
  const int kt = rem / ntn, nt = rem % ntn;

  __shared__ float tile[32][33];
  const int tx = threadIdx.x & 31, ty = threadIdx.x >> 5;
#pragma unroll
  for (int r = 0; r < 4; ++r) {
    int k = kt * 32 + ty + r * 8;
    tile[ty + r * 8][tx] = src[(size_t)k * Nd + nt * 32 + tx];
  }
  __syncthreads();
#pragma unroll
  for (int r = 0; r < 4; ++r) {
    int n = nt * 32 + ty + r * 8;
    dst[(size_t)n * Kd + kt * 32 + tx] = (short)f2bf(tile[tx][ty + r * 8]);
  }
}

// ---------------- input projection: h = x @ Wi + bi (K=16); writes f32 + bf16 ----------------
__global__ __launch_bounds__(256) void inproj_kernel(
    const float* __restrict__ x, const float* __restrict__ Wi,
    const float* __restrict__ bi, float* __restrict__ h, short* __restrict__ hb) {
  __shared__ float xs[16];
  const int i = blockIdx.x, j = threadIdx.x;
  if (j < 16) xs[j] = x[(size_t)i * 16 + j];
  __syncthreads();
  float acc = bi[j];
#pragma unroll
  for (int k = 0; k < 16; ++k) acc += xs[k] * Wi[k * 256 + j];
  h[(size_t)i * 256 + j] = acc;
  hb[(size_t)i * 256 + j] = (short)f2bf(acc);
}

// ---------------- MFMA bf16 GEMM, BK=128, split-K via blockIdx.z ----------------
// A bf16 [M][K], Bt bf16 [N][K]. Block covers K range [z*kpb, (z+1)*kpb).
// OUTBF=1 -> bf16 output (no split). OUTBF=0 -> f32 partial at Cf + z*M*N.
// ACT=1 (relu) only valid unsplit. Bias added by z==0 only.
template <int ACT, int OUTBF>
__global__ __launch_bounds__(256) void gemm_bf16(
    const short* __restrict__ A, const short* __restrict__ Bt,
    const float* __restrict__ bias, float* __restrict__ Cf, short* __restrict__ Cb,
    int M, int N, int K, int kpb) {
  __shared__ short As[64 * 128];
  __shared__ short Bs[64 * 128];

  const int t = threadIdx.x;
  const int bm = blockIdx.y, bn = blockIdx.x, bz = blockIdx.z;
  const int srow = t >> 2, sq = t & 3;
  const int lane = t & 63, wid = t >> 6;
  const int wr = wid >> 1, wc = wid & 1;
  const int fr = lane & 15, fs = lane >> 4;
  const int rx = srow & 7;

  f32x4 acc[2][2];
#pragma unroll
  for (int m = 0; m < 2; ++m)
#pragma unroll
    for (int n = 0; n < 2; ++n) acc[m][n] = (f32x4){0.f, 0.f, 0.f, 0.f};

  const int kbase = bz * kpb;
  const short* ap = A + (size_t)(bm * 64 + srow) * K + kbase;
  const int ng = bn * 64 + srow;
  const short* bp = Bt + (size_t)ng * K + kbase;

  const int ar0 = wr * 32 + fr, ar1 = ar0 + 16;
  const int bc0 = wc * 32 + fr, bc1 = bc0 + 16;

  for (int k0 = 0; k0 < kpb; k0 += 128) {
    bf16x8 av[4], bv[4];
#pragma unroll
    for (int i = 0; i < 4; ++i) av[i] = *(const bf16x8*)(ap + k0 + (sq * 4 + i) * 8);
    if (ng < N) {
#pragma unroll
      for (int i = 0; i < 4; ++i) bv[i] = *(const bf16x8*)(bp + k0 + (sq * 4 + i) * 8);
    } else {
#pragma unroll
      for (int i = 0; i < 4; ++i) bv[i] = (bf16x8){0, 0, 0, 0, 0, 0, 0, 0};
    }
    __syncthreads();  // prior-tile reads done before overwrite (no-op first iter)
#pragma unroll
    for (int i = 0; i < 4; ++i) {
      const int s = sq * 4 + i;
      *(bf16x8*)(As + srow * 128 + ((s ^ rx) * 8)) = av[i];
      *(bf16x8*)(Bs + srow * 128 + ((s ^ rx) * 8)) = bv[i];
    }
    __syncthreads();

#pragma unroll
    for (int ks = 0; ks < 4; ++ks) {
      const int u = ks * 4 + fs;
      bf16x8 a0 = *(const bf16x8*)(As + ar0 * 128 + ((u ^ (ar0 & 7)) * 8));
      bf16x8 a1 = *(const bf16x8*)(As + ar1 * 128 + ((u ^ (ar1 & 7)) * 8));
      bf16x8 b0 = *(const bf16x8*)(Bs + bc0 * 128 + ((u ^ (bc0 & 7)) * 8));
      bf16x8 b1 = *(const bf16x8*)(Bs + bc1 * 128 + ((u ^ (bc1 & 7)) * 8));
      acc[0][0] = __builtin_amdgcn_mfma_f32_16x16x32_bf16(a0, b0, acc[0][0], 0, 0, 0);
      acc[0][1] = __builtin_amdgcn_mfma_f32_16x16x32_bf16(a0, b1, acc[0][1], 0, 0, 0);
      acc[1][0] = __builtin_amdgcn_mfma_f32_16x16x32_bf16(a1, b0, acc[1][0], 0, 0, 0);
      acc[1][1] = __builtin_amdgcn_mfma_f32_16x16x32_bf16(a1, b1, acc[1][1], 0, 0, 0);
    }
  }

#pragma unroll
  for (int n = 0; n < 2; ++n) {
    const int col = bn * 64 + wc * 32 + n * 16 + fr;
    if (col >= N) continue;
    const float bvv = (bz == 0) ? bias[col] : 0.f;
#pragma unroll
    for (int m = 0; m < 2; ++m) {
      const int rbase = bm * 64 + wr * 32 + m * 16 + fs * 4;
#pragma unroll
      for (int j = 0; j < 4; ++j) {
        float v = acc[m][n][j] + bvv;
        if (ACT == 1) v = fmaxf(v, 0.f);
        if (OUTBF) {
          Cb[(size_t)(rbase + j) * N + col] = (short)f2bf(v);
        } else {
          Cf[(size_t)(bz * M + rbase + j) * N + col] = v;
        }
      }
    }
  }
}

// ---------------- MFMA block-diagonal flash attention (bf16 qkv in, bf16 out) ----------------
__global__ __launch_bounds__(256) void attn_mfma(
    const short* __restrict__ qkv, const int* __restrict__ starts,
    short* __restrict__ out) {
  const int g = blockIdx.x >> 3;
  const int h = blockIdx.x & 7;
  const int t = threadIdx.x;
  const int lane = t & 63, w = t >> 6;
  const int fr = lane & 15, fs = lane >> 4;
  const int js = starts[g], je = starts[g + 1];
  const int Lg = je - js;

  __shared__ __align__(16) short Ks[128][40];
  __shared__ __align__(16) short Vt[32][128];
  __shared__ __align__(16) short Ps[4][16][128];

  const float scale = 0.17677669529663687f;  // 1/sqrt(32)
  const bf16x8 bz8 = (bf16x8){0, 0, 0, 0, 0, 0, 0, 0};

  bf16x8 qf[4];
  f32x4 oa[4][2];
  float mrow[4][4], lrow[4][4];
#pragma unroll
  for (int tt = 0; tt < 4; ++tt) {
    const int q0 = js + (w + tt * 4) * 16;
    const int row = min(q0 + fr, 2047);
    qf[tt] = *(const bf16x8*)(qkv + (size_t)row * 768 + h * 32 + fs * 8);
    oa[tt][0] = (f32x4){0.f, 0.f, 0.f, 0.f};
    oa[tt][1] = (f32x4){0.f, 0.f, 0.f, 0.f};
#pragma unroll
    for (int j = 0; j < 4; ++j) { mrow[tt][j] = -3.0e38f; lrow[tt][j] = 0.f; }
  }

  const int nch = (Lg + 127) >> 7;
  for (int c = 0; c < nch; ++c) {
    const int c0 = js + (c << 7);
    __syncthreads();
    {
      const int r = t >> 1, half = t & 1;
      const int jr = c0 + r;
      bf16x8 k0 = bz8, k1 = bz8, v0 = bz8, v1 = bz8;
      if (jr < je) {
        const short* kp = qkv + (size_t)jr * 768 + 256 + h * 32 + half * 16;
        k0 = *(const bf16x8*)kp;
        k1 = *(const bf16x8*)(kp + 8);
        v0 = *(const bf16x8*)(kp + 256);
        v1 = *(const bf16x8*)(kp + 264);
      }
      *(bf16x8*)&Ks[r][half * 16] = k0;
      *(bf16x8*)&Ks[r][half * 16 + 8] = k1;
#pragma unroll
      for (int i = 0; i < 8; ++i) {
        const int d0 = half * 16 + i;
        const int d1 = d0 + 8;
        Vt[d0][((((r >> 3) ^ (d0 & 7)) << 3) | (r & 7))] = v0[i];
        Vt[d1][((((r >> 3) ^ (d1 & 7)) << 3) | (r & 7))] = v1[i];
      }
    }
    __syncthreads();

#pragma unroll
    for (int tt = 0; tt < 4; ++tt) {
      if ((w + tt * 4) * 16 >= Lg) continue;
      f32x4 s[8];
#pragma unroll
      for (int jt = 0; jt < 8; ++jt) {
        const bf16x8 kf = *(const bf16x8*)&Ks[jt * 16 + fr][fs * 8];
        s[jt] = __builtin_amdgcn_mfma_f32_16x16x32_bf16(
            qf[tt], kf, (f32x4){0.f, 0.f, 0.f, 0.f}, 0, 0, 0);
      }
#pragma unroll
      for (int jt = 0; jt < 8; ++jt) {
        const bool valid = (c0 + jt * 16 + fr) < je;
#pragma unroll
        for (int j = 0; j < 4; ++j) s[jt][j] = valid ? s[jt][j] * scale : -3.0e38f;
      }
#pragma unroll
      for (int j = 0; j < 4; ++j) {
        float mx = s[0][j];
#pragma unroll
        for (int jt = 1; jt < 8; ++jt) mx = fmaxf(mx, s[jt][j]);
        mx = fmaxf(mx, __shfl_xor(mx, 1, 64));
        mx = fmaxf(mx, __shfl_xor(mx, 2, 64));
        mx = fmaxf(mx, __shfl_xor(mx, 4, 64));
        mx = fmaxf(mx, __shfl_xor(mx, 8, 64));
        const float mn = fmaxf(mrow[tt][j], mx);
        const float corr = __expf(mrow[tt][j] - mn);
        mrow[tt][j] = mn;
        float rs = 0.f;
#pragma unroll
        for (int jt = 0; jt < 8; ++jt) {
          const float p = __expf(s[jt][j] - mn);
          s[jt][j] = p;
          rs += p;
        }
        rs += __shfl_xor(rs, 1, 64);
        rs += __shfl_xor(rs, 2, 64);
        rs += __shfl_xor(rs, 4, 64);
        rs += __shfl_xor(rs, 8, 64);
        lrow[tt][j] = lrow[tt][j] * corr + rs;
        oa[tt][0][j] *= corr;
        oa[tt][1][j] *= corr;
      }
#pragma unroll
      for (int jt = 0; jt < 8; ++jt) {
#pragma unroll
        for (int j = 0; j < 4; ++j) {
          const int q = fs * 4 + j;
          Ps[w][q][((((jt * 2 + (fr >> 3)) ^ (q & 7)) << 3) | (fr & 7))] =
              (short)f2bf(s[jt][j]);
        }
      }
#pragma unroll
      for (int jq = 0; jq < 4; ++jq) {
        const int slot = ((jq * 4 + fs) ^ (fr & 7)) << 3;
        const bf16x8 pf = *(const bf16x8*)&Ps[w][fr][slot];
#pragma unroll
        for (int nt = 0; nt < 2; ++nt) {
          const bf16x8 vf = *(const bf16x8*)&Vt[nt * 16 + fr][slot];
          oa[tt][nt] = __builtin_amdgcn_mfma_f32_16x16x32_bf16(pf, vf, oa[tt][nt], 0, 0, 0);
        }
      }
    }
  }

#pragma unroll
  for (int tt = 0; tt < 4; ++tt) {
    if ((w + tt * 4) * 16 >= Lg) continue;
    const int q0 = js + (w + tt * 4) * 16;
#pragma unroll
    for (int j = 0; j < 4; ++j) {
      const int node = q0 + fs * 4 + j;
      if (node < je) {
        const float inv = 1.f / lrow[tt][j];
        out[(size_t)node * 256 + h * 32 + fr] = (short)f2bf(oa[tt][0][j] * inv);
        out[(size_t)node * 256 + h * 32 + 16 + fr] = (short)f2bf(oa[tt][1][j] * inv);
      }
    }
  }
}

// ---------------- fused residual + P-partial sum + LayerNorm; writes f32 + bf16 ----------------
template <int P>
__global__ __launch_bounds__(256) void ln_kernel(
    const float* __restrict__ base, const float* __restrict__ delta,
    const float* __restrict__ s, const float* __restrict__ b,
    float* __restrict__ outf, short* __restrict__ outb) {
  const int row = blockIdx.x * 4 + (threadIdx.x >> 6);
  const int lane = threadIdx.x & 63;
  const float4 xa = *(const float4*)(base + (size_t)row * 256 + lane * 4);
  float4 v = xa;
#pragma unroll
  for (int p = 0; p < P; ++p) {
    const float4 xb = *(const float4*)(delta + (size_t)(p * 2048 + row) * 256 + lane * 4);
    v.x += xb.x; v.y += xb.y; v.z += xb.z; v.w += xb.w;
  }
  float sum = v.x + v.y + v.z + v.w;
  sum = wave_sum64(sum);
  const float mean = sum * (1.f / 256.f);
  float4 d = make_float4(v.x - mean, v.y - mean, v.z - mean, v.w - mean);
  float sq = d.x * d.x + d.y * d.y + d.z * d.z + d.w * d.w;
  sq = wave_sum64(sq);
  const float rs = rsqrtf(sq * (1.f / 256.f) + 1e-5f);
  const float4 sv = *(const float4*)(s + lane * 4);
  const float4 bv = *(const float4*)(b + lane * 4);
  float4 o = make_float4(d.x * rs * sv.x + bv.x, d.y * rs * sv.y + bv.y,
                         d.z * rs * sv.z + bv.z, d.w * rs * sv.w + bv.w);
  *(float4*)(outf + (size_t)row * 256 + lane * 4) = o;
  short4 ob;
  ob.x = (short)f2bf(o.x); ob.y = (short)f2bf(o.y);
  ob.z = (short)f2bf(o.z); ob.w = (short)f2bf(o.w);
  *(short4*)(outb + (size_t)row * 256 + lane * 4) = ob;
}

// ---------------- lat head: GEMM (N=32, K=256) + fused row-normalize ----------------
// Grid (M/64); 4 waves each own 16 rows. Output lat_out[row*32+col] normalized.
__global__ __launch_bounds__(256) void lat_kernel(
    const short* __restrict__ A, const short* __restrict__ Bt,
    const float* __restrict__ bias, float* __restrict__ out) {
  __shared__ short As[64 * 128];
  __shared__ short Bs[64 * 128];
  const int t = threadIdx.x;
  const int bm = blockIdx.x;
  const int srow = t >> 2, sq = t & 3;
  const int lane = t & 63, w = t >> 6;
  const int fr = lane & 15, fs = lane >> 4;
  const int rx = srow & 7;

  f32x4 acc[2];
  acc[0] = (f32x4){0.f, 0.f, 0.f, 0.f};
  acc[1] = (f32x4){0.f, 0.f, 0.f, 0.f};

  const short* ap = A + (size_t)(bm * 64 + srow) * 256;
  const short* bp = Bt + (size_t)srow * 256;
  const int ar = w * 16 + fr;

  for (int k0 = 0; k0 < 256; k0 += 128) {
    bf16x8 av[4], bv[4];
#pragma unroll
    for (int i = 0; i < 4; ++i) av[i] = *(const bf16x8*)(ap + k0 + (sq * 4 + i) * 8);
    if (srow < 32) {
#pragma unroll
      for (int i = 0; i < 4; ++i) bv[i] = *(const bf16x8*)(bp + k0 + (sq * 4 + i) * 8);
    } else {
#pragma unroll
      for (int i = 0; i < 4; ++i) bv[i] = (bf16x8){0, 0, 0, 0, 0, 0, 0, 0};
    }
    __syncthreads();
#pragma unroll
    for (int i = 0; i < 4; ++i) {
      const int s = sq * 4 + i;
      *(bf16x8*)(As + srow * 128 + ((s ^ rx) * 8)) = av[i];
      *(bf16x8*)(Bs + srow * 128 + ((s ^ rx) * 8)) = bv[i];
    }
    __syncthreads();
#pragma unroll
    for (int ks = 0; ks < 4; ++ks) {
      const int u = ks * 4 + fs;
      bf16x8 a0 = *(const bf16x8*)(As + ar * 128 + ((u ^ (ar & 7)) * 8));
      bf16x8 b0 = *(const bf16x8*)(Bs + fr * 128 + ((u ^ (fr & 7)) * 8));
      bf16x8 b1 = *(const bf16x8*)(Bs + (16 + fr) * 128 + ((u ^ ((16 + fr) & 7)) * 8));
      acc[0] = __builtin_amdgcn_mfma_f32_16x16x32_bf16(a0, b0, acc[0], 0, 0, 0);
      acc[1] = __builtin_amdgcn_mfma_f32_16x16x32_bf16(a0, b1, acc[1], 0, 0, 0);
    }
  }

  const float b0v = bias[fr], b1v = bias[16 + fr];
#pragma unroll
  for (int j = 0; j < 4; ++j) {
    const int row = bm * 64 + w * 16 + fs * 4 + j;
    float v0 = acc[0][j] + b0v;
    float v1 = acc[1][j] + b1v;
    float ss = v0 * v0 + v1 * v1;
    ss += __shfl_xor(ss, 1, 64);
    ss += __shfl_xor(ss, 2, 64);
    ss += __shfl_xor(ss, 4, 64);
    ss += __shfl_xor(ss, 8, 64);
    const float inv = 5.656854249492381f / fmaxf(sqrtf(ss), 1e-12f);
    out[(size_t)row * 32 + fr] = v0 * inv;
    out[(size_t)row * 32 + 16 + fr] = v1 * inv;
  }
}

// ---------------- beta head ----------------
__global__ __launch_bounds__(256) void beta_kernel(
    const float* __restrict__ bh, const float* __restrict__ w,
    const float* __restrict__ b2b, float* __restrict__ beta) {
  const int row = blockIdx.x * 4 + (threadIdx.x >> 6);
  const int lane = threadIdx.x & 63;
  float p = bh[(size_t)row * 128 + lane] * w[lane] +
            bh[(size_t)row * 128 + 64 + lane] * w[64 + lane];
  p = wave_sum64(p);
  if (lane == 0) {
    float x = p + b2b[0];
    float sgm = 1.f / (1.f + __expf(-x));
    sgm = fminf(fmaxf(sgm, 1e-6f), 1.f - 1e-6f);
    beta[row] = sgm;
  }
}

// ---------------- launch ----------------
extern "C" void kernel_launch(void* const* d_in, const int* in_sizes, int n_in,
                              void* d_out, int out_size, void* d_ws, size_t ws_size,
                              hipStream_t stream) {
  const int N = 2048, D = 256, FF = 1024, L = 4;

  const float* x     = (const float*)d_in[0];
  const int*   batch = (const int*)d_in[2];
  const float* Wi    = (const float*)d_in[3];
  const float* bi    = (const float*)d_in[4];
  const float* qkv_w = (const float*)d_in[5];
  const float* qkv_b = (const float*)d_in[6];
  const float* out_w = (const float*)d_in[7];
  const float* out_b = (const float*)d_in[8];
  const float* ff1_w = (const float*)d_in[9];
  const float* ff1_b = (const float*)d_in[10];
  const float* ff2_w = (const float*)d_in[11];
  const float* ff2_b = (const float*)d_in[12];
  const float* ln1_s = (const float*)d_in[13];
  const float* ln1_b = (const float*)d_in[14];
  const float* ln2_s = (const float*)d_in[15];
  const float* ln2_b = (const float*)d_in[16];
  const float* lat_w = (const float*)d_in[17];
  const float* lat_b = (const float*)d_in[18];
  const float* b1_w  = (const float*)d_in[19];
  const float* b1_b  = (const float*)d_in[20];
  const float* b2_w  = (const float*)d_in[21];
  const float* b2_b  = (const float*)d_in[22];

  float* ws = (float*)d_ws;
  float* h      = ws;                              // N*D f32
  float* tmp    = h + (size_t)N * D;               // 4*N*D f32 (split-K partials)
  float* bh     = tmp + (size_t)4 * N * D;         // N*128 f32
  int*  starts  = (int*)(bh + (size_t)N * 128);    // 32 ints
  short* hb     = (short*)(starts + 32);           // N*D bf16
  short* qkvb   = hb + (size_t)N * D;              // N*3D bf16
  short* attnb  = qkvb + (size_t)N * 3 * D;        // N*D bf16
  short* ffb    = attnb + (size_t)N * D;           // N*FF bf16
  short* qkv_t  = ffb + (size_t)N * FF;
  short* out_t  = qkv_t + (size_t)L * 768 * 256;
  short* ff1_t  = out_t + (size_t)L * 256 * 256;
  short* ff2_t  = ff1_t + (size_t)L * 1024 * 256;
  short* b1_t   = ff2_t + (size_t)L * 256 * 1024;
  short* lat_t  = b1_t + (size_t)128 * 256;

  float* beta_out = (float*)d_out;
  float* lat_out  = beta_out + N;

  pack_weights<<<3113, 256, 0, stream>>>(qkv_w, out_w, ff1_w, ff2_w, b1_w, lat_w,
                                         qkv_t, out_t, ff1_t, ff2_t, b1_t, lat_t,
                                         batch, starts);
  inproj_kernel<<<N, 256, 0, stream>>>(x, Wi, bi, h, hb);

  for (int l = 0; l < L; ++l) {
    // qkv = h @ qkv_w + b  -> bf16
    gemm_bf16<0, 1><<<dim3(12, 32, 1), 256, 0, stream>>>(
        hb, qkv_t + (size_t)l * 768 * 256, qkv_b + (size_t)l * 768,
        nullptr, qkvb, N, 768, 256, 256);
    attn_mfma<<<16 * 8, 256, 0, stream>>>(qkvb, starts, attnb);
    // out-proj, split-K=2 -> f32 partials tmp[0..1]
    gemm_bf16<0, 0><<<dim3(4, 32, 2), 256, 0, stream>>>(
        attnb, out_t + (size_t)l * 256 * 256, out_b + (size_t)l * 256,
        tmp, nullptr, N, 256, 256, 128);
    ln_kernel<2><<<N / 4, 256, 0, stream>>>(h, tmp, ln1_s + (size_t)l * D,
                                            ln1_b + (size_t)l * D, h, hb);
    // ff1 = relu(h @ ff1_w + b) -> bf16
    gemm_bf16<1, 1><<<dim3(16, 32, 1), 256, 0, stream>>>(
        hb, ff1_t + (size_t)l * FF * 256, ff1_b + (size_t)l * FF,
        nullptr, ffb, N, FF, 256, 256);
    // ff2, split-K=4 -> f32 partials tmp[0..3]
    gemm_bf16<0, 0><<<dim3(4, 32, 4), 256, 0, stream>>>(
        ffb, ff2_t + (size_t)l * 256 * FF, ff2_b + (size_t)l * 256,
        tmp, nullptr, N, 256, 1024, 256);
    ln_kernel<4><<<N / 4, 256, 0, stream>>>(h, tmp, ln2_s + (size_t)l * D,
                                            ln2_b + (size_t)l * D, h, hb);
  }

  // lat head (GEMM + fused normalize)
  lat_kernel<<<N / 64, 256, 0, stream>>>(hb, lat_t, lat_b, lat_out);
  // beta head
  gemm_bf16<1, 0><<<dim3(2, 32, 1), 256, 0, stream>>>(
      hb, b1_t, b1_b, bh, nullptr, N, 128, 256, 256);
  beta_kernel<<<N / 4, 256, 0, stream>>>(bh, b2_w, b2_b, beta_out);
}